// Round 5
// baseline (7469.432 us; speedup 1.0000x reference)
//
#include <hip/hip_runtime.h>
#include <cmath>

// (B, L, D, H) = (256, 32, 512, 512)
#define B_   256
#define L_   32
#define H_   512
#define NH5  2560   // 5*H
#define N2   5120   // 2*NH5 : [al | ar] output width
#define SCALE 0.044194173824159216f  // 1/sqrt(H)

// ---------------- persistent device state (re-initialized every launch) ----
__device__ float g_h [B_*L_*H_];          // [b][slot][j] node hidden
__device__ float g_c [B_*L_*H_];          // [b][slot][j] node cell
__device__ float g_al[(size_t)B_*L_*NH5]; // [b][slot][k] Wl @ h_slot
__device__ float g_ar[(size_t)B_*L_*NH5]; // [b][slot][k] Wr @ h_slot
__device__ float g_logit[B_*L_];          // pair logit keyed by LEFT slot
__device__ int   g_list[B_*L_];           // active slot list (sequence order)
__device__ int   g_count[B_];             // active node count
__device__ int   g_merged[B_];            // slot merged last iter (-1 done, -2 init)
__device__ int   g_mpos[B_];              // list position of last merge
__device__ int   g_off[B_];               // exclusive prefix of lengths
__device__ int   g_rows[B_*L_];           // ordered compact list of active rows
__device__ int   g_nrows;
__device__ int   g_done[B_];              // monotone per-batch block-arrival counter

__device__ __forceinline__ float sigm(float x) { return 1.0f / (1.0f + expf(-x)); }

// ---------------- init: prefix-scan lengths, ordered row list --------------
__global__ __launch_bounds__(256) void scan_init(const int* __restrict__ length) {
  __shared__ int sw[4];
  const int t = threadIdx.x;
  const int len = length[t];
  int v = len;
#pragma unroll
  for (int off = 1; off < 64; off <<= 1) {
    int o = __shfl_up(v, off, 64);
    if ((t & 63) >= off) v += o;
  }
  if ((t & 63) == 63) sw[t >> 6] = v;
  __syncthreads();
  int base = 0;
  for (int w = 0; w < (t >> 6); w++) base += sw[w];
  const int incl = base + v;
  g_off[t] = incl - len;
  if (t == 255) g_nrows = incl;
  g_count[t] = len; g_merged[t] = -2; g_mpos[t] = 0; g_done[t] = 0;
}

__global__ __launch_bounds__(32) void fill_rows() {
  const int b = blockIdx.x, t = threadIdx.x;
  g_list[b*L_ + t] = t;
  if (t < g_count[b]) g_rows[g_off[b] + t] = b*L_ + t;   // sorted by (b,slot)
}

// ---------------- big row-compacted GEMMs (128x128, BK=16, LDS dbuf) -------
// MODE 0: word GEMM  A=x rows   -> g_h|g_c (+b_word)   N=1024
// MODE 1: leaf GEMM  A=g_h rows -> g_al|g_ar           N=5120
template<int MODE>
__global__ __launch_bounds__(256) void gemm_big(
    const float* __restrict__ Aext,
    const float* __restrict__ Bm,
    const float* __restrict__ bias)
{
  const int NR = g_nrows;
  const int m0 = blockIdx.y * 128;
  if (m0 >= NR) return;                      // uniform early exit
  const int n0 = blockIdx.x * 128;

  const int tid = threadIdx.x;
  const int w = tid >> 6, l = tid & 63;
  const int tx = (w & 1) * 8 + (l & 7);      // 0..15 (n dir)
  const int ty = (w >> 1) * 8 + (l >> 3);    // 0..15 (m dir)

  __shared__ float As[2][16][128];           // 16 KB
  __shared__ float Bs[2][16][128];           // 16 KB

  const int ra = tid >> 1, qa = (tid & 1) * 8;   // 128 rows x 16 k, 8 floats/thread

  const float* Abase = (MODE == 0) ? Aext : g_h;
  int mr = m0 + ra; if (mr >= NR) mr = NR - 1;
  const float* aptr = Abase + (size_t)g_rows[mr] * 512 + qa;

  const float* bptr;
  {
    int nrow = n0 + ra;
    if (MODE == 0) bptr = Bm + (size_t)nrow * 512 + qa;
    else bptr = Bm + (nrow < NH5 ? (size_t)nrow * 1024
                                 : (size_t)(nrow - NH5) * 1024 + 512) + qa;
  }

  float4 a0 = *(const float4*)(aptr),     a1 = *(const float4*)(aptr + 4);
  float4 b0 = *(const float4*)(bptr),     b1 = *(const float4*)(bptr + 4);
  float acc[8][8] = {};

  for (int k0 = 0; k0 < 512; k0 += 16) {
    const int buf = (k0 >> 4) & 1;
    As[buf][qa+0][ra]=a0.x; As[buf][qa+1][ra]=a0.y; As[buf][qa+2][ra]=a0.z; As[buf][qa+3][ra]=a0.w;
    As[buf][qa+4][ra]=a1.x; As[buf][qa+5][ra]=a1.y; As[buf][qa+6][ra]=a1.z; As[buf][qa+7][ra]=a1.w;
    Bs[buf][qa+0][ra]=b0.x; Bs[buf][qa+1][ra]=b0.y; Bs[buf][qa+2][ra]=b0.z; Bs[buf][qa+3][ra]=b0.w;
    Bs[buf][qa+4][ra]=b1.x; Bs[buf][qa+5][ra]=b1.y; Bs[buf][qa+6][ra]=b1.z; Bs[buf][qa+7][ra]=b1.w;
    __syncthreads();                         // single barrier per step (dbuf)
    if (k0 + 16 < 512) {
      a0 = *(const float4*)(aptr + k0 + 16); a1 = *(const float4*)(aptr + k0 + 20);
      b0 = *(const float4*)(bptr + k0 + 16); b1 = *(const float4*)(bptr + k0 + 20);
    }
#pragma unroll
    for (int k = 0; k < 16; k++) {
      float af[8], bf[8];
#pragma unroll
      for (int c = 0; c < 2; c++) {
        float4 t = *(const float4*)&As[buf][k][ty*8 + 4*c];
        af[4*c+0]=t.x; af[4*c+1]=t.y; af[4*c+2]=t.z; af[4*c+3]=t.w;
      }
#pragma unroll
      for (int c = 0; c < 2; c++) {
        float4 t = *(const float4*)&Bs[buf][k][tx*8 + 4*c];
        bf[4*c+0]=t.x; bf[4*c+1]=t.y; bf[4*c+2]=t.z; bf[4*c+3]=t.w;
      }
#pragma unroll
      for (int i = 0; i < 8; i++)
#pragma unroll
        for (int j = 0; j < 8; j++)
          acc[i][j] = fmaf(af[i], bf[j], acc[i][j]);
    }
  }

#pragma unroll
  for (int i = 0; i < 8; i++) {
    int mrow = m0 + ty*8 + i;
    if (mrow >= NR) continue;
    int crow = g_rows[mrow];
#pragma unroll
    for (int j = 0; j < 8; j++) {
      int n = n0 + tx*8 + j;
      float v = acc[i][j];
      if (MODE == 0) {
        v += bias[n];
        if (n < H_) g_h[(size_t)crow*H_ + n]        = v;
        else        g_c[(size_t)crow*H_ + (n - H_)] = v;
      } else {
        if (n < NH5) g_al[(size_t)crow*NH5 + n]         = v;
        else         g_ar[(size_t)crow*NH5 + (n - NH5)] = v;
      }
    }
  }
}

// ---------------- iteration-0 logits ---------------------------------------
__global__ __launch_bounds__(256) void iter0_logits(const int* __restrict__ length,
                                                    const float* __restrict__ bc,
                                                    const float* __restrict__ qv) {
  __shared__ float sred[4];
  const int p = blockIdx.x, b = blockIdx.y;
  if (p >= length[b] - 1) return;            // inactive pair: never read
  const float* al = g_al + (size_t)(b*L_ + p)*NH5;
  const float* ar = g_ar + (size_t)(b*L_ + p + 1)*NH5;
  const float* cl = g_c  + (size_t)(b*L_ + p)*H_;
  const float* cr = g_c  + (size_t)(b*L_ + p + 1)*H_;
  float part = 0.f;
#pragma unroll
  for (int jj = 0; jj < H_/256; jj++) {
    int j = threadIdx.x + jj*256;
    float vi  = al[j]       + ar[j]       + bc[j];
    float vfl = al[H_+j]    + ar[H_+j]    + bc[H_+j];
    float vfr = al[2*H_+j]  + ar[2*H_+j]  + bc[2*H_+j];
    float vu  = al[3*H_+j]  + ar[3*H_+j]  + bc[3*H_+j];
    float vo  = al[4*H_+j]  + ar[4*H_+j]  + bc[4*H_+j];
    float c = cl[j]*sigm(vfl+1.f) + cr[j]*sigm(vfr+1.f) + tanhf(vu)*sigm(vi);
    float h = sigm(vo)*tanhf(c);
    part = fmaf(qv[j], h, part);
  }
#pragma unroll
  for (int off = 32; off; off >>= 1) part += __shfl_down(part, off, 64);
  if ((threadIdx.x & 63) == 0) sred[threadIdx.x >> 6] = part;
  __syncthreads();
  if (threadIdx.x == 0)
    g_logit[b*L_ + p] = (sred[0]+sred[1]+sred[2]+sred[3]) * SCALE;
}

// ---------------- per-batch select + merge body (whole block) --------------
__device__ void select_body(int b, int iter,
                            const int* __restrict__ length,
                            const float* __restrict__ bc,
                            const float* __restrict__ qv)
{
  __shared__ float sred[4];
  __shared__ int s_sel[3];
  const int tid = threadIdx.x;

  const bool active = iter < (length[b] - 1);
  if (!active) {
    if (tid == 0) g_merged[b] = -1;
    __syncthreads();
    return;
  }

  const int m     = g_count[b];
  const int pslot = g_merged[b];
  const int ppos  = g_mpos[b];
  int* list = g_list + b*L_;

  // ---- refresh the <=2 dirty pairs, half-block each ----
  if (iter > 0 && pslot >= 0) {
    const int half = tid >> 7, lt = tid & 127;
    int sl = -1, sr = -1;
    if (half == 0) { if (ppos > 0)     { sl = list[ppos-1]; sr = list[ppos];   } }
    else           { if (ppos < m - 1) { sl = list[ppos];   sr = list[ppos+1]; } }
    float part = 0.f;
    if (sl >= 0) {
      const float* al = g_al + (size_t)(b*L_+sl)*NH5;
      const float* ar = g_ar + (size_t)(b*L_+sr)*NH5;
      const float* cl = g_c  + (size_t)(b*L_+sl)*H_;
      const float* cr = g_c  + (size_t)(b*L_+sr)*H_;
#pragma unroll
      for (int jj = 0; jj < H_/128; jj++) {
        int j = lt + jj*128;
        float vi  = al[j]       + ar[j]       + bc[j];
        float vfl = al[H_+j]    + ar[H_+j]    + bc[H_+j];
        float vfr = al[2*H_+j]  + ar[2*H_+j]  + bc[2*H_+j];
        float vu  = al[3*H_+j]  + ar[3*H_+j]  + bc[3*H_+j];
        float vo  = al[4*H_+j]  + ar[4*H_+j]  + bc[4*H_+j];
        float c = cl[j]*sigm(vfl+1.f) + cr[j]*sigm(vfr+1.f) + tanhf(vu)*sigm(vi);
        float h = sigm(vo)*tanhf(c);
        part = fmaf(qv[j], h, part);
      }
    }
#pragma unroll
    for (int off = 32; off; off >>= 1) part += __shfl_down(part, off, 64);
    if ((tid & 63) == 0) sred[tid >> 6] = part;
    __syncthreads();
    if (tid == 0   && ppos > 0)     g_logit[b*L_ + list[ppos-1]] = (sred[0]+sred[1])*SCALE;
    if (tid == 128 && ppos < m - 1) g_logit[b*L_ + list[ppos]]   = (sred[2]+sred[3])*SCALE;
  }
  __syncthreads();   // refreshed g_logit visible block-wide; sred reusable

  // ---- wave-parallel argmax, first-max tie-break (lowest index) ----
  if (tid < 64) {
    float lg = -1e30f; int idx = tid;
    if (tid < m - 1) lg = g_logit[b*L_ + list[tid]];
#pragma unroll
    for (int off = 32; off; off >>= 1) {
      float olg = __shfl_down(lg, off, 64);
      int   oid = __shfl_down(idx, off, 64);
      if (olg > lg || (olg == lg && oid < idx)) { lg = olg; idx = oid; }
    }
    if (tid == 0) { s_sel[0] = idx; s_sel[1] = list[idx]; s_sel[2] = list[idx+1]; }
  }
  __syncthreads();
  const int pos = s_sel[0], sl = s_sel[1], sr = s_sel[2];

  // ---- merge compose (store h,c into slot sl) ----
  {
    const float* al = g_al + (size_t)(b*L_+sl)*NH5;
    const float* ar = g_ar + (size_t)(b*L_+sr)*NH5;
    float*       cl = g_c  + (size_t)(b*L_+sl)*H_;
    const float* cr = g_c  + (size_t)(b*L_+sr)*H_;
    float*       hl = g_h  + (size_t)(b*L_+sl)*H_;
#pragma unroll
    for (int jj = 0; jj < H_/256; jj++) {
      int j = tid + jj*256;
      float vi  = al[j]       + ar[j]       + bc[j];
      float vfl = al[H_+j]    + ar[H_+j]    + bc[H_+j];
      float vfr = al[2*H_+j]  + ar[2*H_+j]  + bc[2*H_+j];
      float vu  = al[3*H_+j]  + ar[3*H_+j]  + bc[3*H_+j];
      float vo  = al[4*H_+j]  + ar[4*H_+j]  + bc[4*H_+j];
      float c = cl[j]*sigm(vfl+1.f) + cr[j]*sigm(vfr+1.f) + tanhf(vu)*sigm(vi);
      float h = sigm(vo)*tanhf(c);
      cl[j] = c; hl[j] = h;                  // same-thread j: no RAW hazard
    }
  }
  __syncthreads();
  if (tid == 0) {
    for (int n = pos+1; n < m-1; n++) list[n] = list[n+1];
    g_count[b]  = m - 1;
    g_merged[b] = sl;
    g_mpos[b]   = pos;
  }
  __syncthreads();
}

// iteration-0 select (logits precomputed by iter0_logits)
__global__ __launch_bounds__(256) void select0(const int* __restrict__ length,
                                               const float* __restrict__ bc,
                                               const float* __restrict__ qv) {
  select_body(blockIdx.x, 0, length, bc, qv);
}

// ---------------- fused iteration fi = 1..30 -------------------------------
// 640 blocks = 8 m-tiles x 80 n-tiles. Each block: 32x64 a-GEMM tile for the
// nodes merged at iter fi-1, fence, bump per-batch done counters. The block
// that brings done[b] to 80*fi (the LAST writer of b's fresh a-vectors) runs
// batch b's select+merge for iter fi inline. No waiting anywhere.
__global__ __launch_bounds__(256) void fused_iter(int fi,
    const int* __restrict__ length,
    const float* __restrict__ bc,
    const float* __restrict__ qv,
    const float* __restrict__ Wc)
{
  const int tid = threadIdx.x;
  const int mt = blockIdx.x / 80, nt = blockIdx.x % 80;
  const int m0b = mt * 32, n0 = nt * 64;

  __shared__ float As[32][32];   // [k][m]
  __shared__ float Bs[32][64];   // [k][n]
  __shared__ int s_slot[32];
  __shared__ int s_claim;

  if (tid < 32) s_slot[tid] = g_merged[m0b + tid];   // merges of iter fi-1
  __syncthreads();

  // A staging: 32 batch-rows x 32 k
  const int ra = tid >> 3, qa = (tid & 7) * 4;
  const int slotA = (s_slot[ra] >= 0) ? s_slot[ra] : 0;   // inactive: dummy row
  const float* aptr = g_h + (size_t)((m0b + ra)*L_ + slotA) * 512 + qa;

  // B staging: 64 n-rows x 32 k
  const int rb = tid >> 2, qb = (tid & 3) * 8;
  const int nr = n0 + rb;
  const float* bptr = (nr < NH5) ? Wc + (size_t)nr * 1024 + qb
                                 : Wc + (size_t)(nr - NH5) * 1024 + 512 + qb;

  const int tx = tid & 15, ty = tid >> 4;

  float4 av  = *(const float4*)(aptr);
  float4 bv0 = *(const float4*)(bptr);
  float4 bv1 = *(const float4*)(bptr + 4);
  float acc[2][4] = {};

  for (int k0 = 0; k0 < 512; k0 += 32) {
    __syncthreads();
    As[qa+0][ra] = av.x;  As[qa+1][ra] = av.y;  As[qa+2][ra] = av.z;  As[qa+3][ra] = av.w;
    Bs[qb+0][rb] = bv0.x; Bs[qb+1][rb] = bv0.y; Bs[qb+2][rb] = bv0.z; Bs[qb+3][rb] = bv0.w;
    Bs[qb+4][rb] = bv1.x; Bs[qb+5][rb] = bv1.y; Bs[qb+6][rb] = bv1.z; Bs[qb+7][rb] = bv1.w;
    __syncthreads();
    if (k0 + 32 < 512) {
      av  = *(const float4*)(aptr + k0 + 32);
      bv0 = *(const float4*)(bptr + k0 + 32);
      bv1 = *(const float4*)(bptr + k0 + 36);
    }
#pragma unroll
    for (int k = 0; k < 32; k++) {
      float2 a2 = *(const float2*)&As[k][ty*2];
      float4 b4 = *(const float4*)&Bs[k][tx*4];
      acc[0][0] = fmaf(a2.x, b4.x, acc[0][0]);
      acc[0][1] = fmaf(a2.x, b4.y, acc[0][1]);
      acc[0][2] = fmaf(a2.x, b4.z, acc[0][2]);
      acc[0][3] = fmaf(a2.x, b4.w, acc[0][3]);
      acc[1][0] = fmaf(a2.y, b4.x, acc[1][0]);
      acc[1][1] = fmaf(a2.y, b4.y, acc[1][1]);
      acc[1][2] = fmaf(a2.y, b4.z, acc[1][2]);
      acc[1][3] = fmaf(a2.y, b4.w, acc[1][3]);
    }
  }

#pragma unroll
  for (int i = 0; i < 2; i++) {
    const int mrow = ty*2 + i;               // 0..31 within tile
    const int slot = s_slot[mrow];
    if (slot < 0) continue;                  // batch inactive: no merge last iter
    size_t base = (size_t)((m0b + mrow)*L_ + slot) * NH5;
    int n = n0 + tx*4;                       // 4-chunks never straddle NH5
    float4 v = make_float4(acc[i][0], acc[i][1], acc[i][2], acc[i][3]);
    if (n < NH5) *(float4*)(g_al + base + n)         = v;
    else         *(float4*)(g_ar + base + (n - NH5)) = v;
  }

  // ---- release + last-arriver claim (no spinning) ----
  __threadfence();                           // my stores visible device-wide
  __syncthreads();                           // all threads' fences done
  bool claim = false;
  if (tid < 32) {
    int old = atomicAdd(&g_done[m0b + tid], 1);
    claim = (old == 80*fi - 1);              // I'm the 80th block for this batch
  }
  unsigned long long mk = __ballot(claim);   // bits 0..31 (wave 0)
  if (tid == 0) s_claim = (int)mk;
  __syncthreads();
  int cm = s_claim;
  if (cm != 0) {
    __threadfence();                         // acquire: fresh al/ar from others
    while (cm != 0) {
      int bi = __ffs(cm) - 1;
      cm &= cm - 1;
      select_body(m0b + bi, fi, length, bc, qv);
    }
  }
}

__global__ __launch_bounds__(256) void write_out(float* __restrict__ out) {
  int b = blockIdx.x;
  for (int j = threadIdx.x; j < H_; j += 256)
    out[(size_t)b*H_ + j] = g_h[(size_t)(b*L_)*H_ + j];   // root always slot 0
}

// ---------------------------------------------------------------------------
extern "C" void kernel_launch(void* const* d_in, const int* in_sizes, int n_in,
                              void* d_out, int out_size, void* d_ws, size_t ws_size,
                              hipStream_t stream)
{
  (void)in_sizes; (void)n_in; (void)out_size; (void)d_ws; (void)ws_size;
  const float* x      = (const float*)d_in[0];
  const int*   length = (const int*)  d_in[1];
  const float* W_word = (const float*)d_in[2];
  const float* b_word = (const float*)d_in[3];
  const float* W_comp = (const float*)d_in[4];
  const float* b_comp = (const float*)d_in[5];
  const float* q      = (const float*)d_in[6];
  float* out = (float*)d_out;

  scan_init<<<1, 256, 0, stream>>>(length);
  fill_rows<<<B_, 32, 0, stream>>>();

  gemm_big<0><<<dim3(1024/128, 64), 256, 0, stream>>>(x, W_word, b_word);
  gemm_big<1><<<dim3(N2/128,   64), 256, 0, stream>>>(nullptr, W_comp, nullptr);

  iter0_logits<<<dim3(L_-1, B_), 256, 0, stream>>>(length, b_comp, q);
  select0<<<B_, 256, 0, stream>>>(length, b_comp, q);

  for (int fi = 1; fi <= L_-2; fi++)
    fused_iter<<<640, 256, 0, stream>>>(fi, length, b_comp, q, W_comp);

  write_out<<<B_, 256, 0, stream>>>(out);
}

// Round 6
// 1752.377 us; speedup vs baseline: 4.2625x; 4.2625x over previous
//
#include <hip/hip_runtime.h>
#include <cmath>

// (B, L, D, H) = (256, 32, 512, 512)
#define B_   256
#define L_   32
#define H_   512
#define NH5  2560   // 5*H
#define N2   5120   // 2*NH5 : [al | ar] output width
#define SCALE 0.044194173824159216f  // 1/sqrt(H)

// ---------------- persistent device state (re-initialized every launch) ----
__device__ float g_h [B_*L_*H_];          // [b][slot][j] node hidden
__device__ float g_c [B_*L_*H_];          // [b][slot][j] node cell
__device__ float g_al[(size_t)B_*L_*NH5]; // [b][slot][k] Wl @ h_slot
__device__ float g_ar[(size_t)B_*L_*NH5]; // [b][slot][k] Wr @ h_slot
__device__ float g_logit[B_*L_];          // pair logit keyed by LEFT slot
__device__ int   g_list[B_*L_];           // active slot list (sequence order)
__device__ int   g_count[B_];             // active node count
__device__ int   g_merged[B_];            // slot merged last iter (-1 done, -2 init)
__device__ int   g_mpos[B_];              // list position of last merge
__device__ int   g_off[B_];               // exclusive prefix of lengths
__device__ int   g_rows[B_*L_];           // ordered compact list of active rows
__device__ int   g_nrows;
__device__ int   g_mlist[2][B_];          // batches merged this iter (parity)
__device__ int   g_cnt[2];

__device__ __forceinline__ float sigm(float x) { return 1.0f / (1.0f + expf(-x)); }

// ---------------- init: prefix-scan lengths + fill lists (one dispatch) ----
__global__ __launch_bounds__(256) void init_all(const int* __restrict__ length) {
  __shared__ int sw[4];
  const int t = threadIdx.x;
  const int len = length[t];
  int v = len;
#pragma unroll
  for (int off = 1; off < 64; off <<= 1) {
    int o = __shfl_up(v, off, 64);
    if ((t & 63) >= off) v += o;
  }
  if ((t & 63) == 63) sw[t >> 6] = v;
  __syncthreads();
  int base = 0;
  for (int w = 0; w < (t >> 6); w++) base += sw[w];
  const int incl = base + v;
  const int off0 = incl - len;
  g_off[t] = off0;
  if (t == 255) g_nrows = incl;
  g_count[t] = len; g_merged[t] = -2; g_mpos[t] = 0;
  if (t == 0) { g_cnt[0] = 0; g_cnt[1] = 0; }
#pragma unroll
  for (int s = 0; s < L_; s++) g_list[t*L_ + s] = s;
  for (int s = 0; s < len; s++) g_rows[off0 + s] = t*L_ + s;  // sorted by (b,slot)
}

// ---------------- big row-compacted GEMMs (128x128, BK=16, LDS dbuf) -------
// MODE 0: word GEMM  A=x rows   -> g_h|g_c (+b_word)   N=1024
// MODE 1: leaf GEMM  A=g_h rows -> g_al|g_ar           N=5120
// grid: x = m-tiles (64, fastest -> same n-tile shares B in L2), y = n-tiles
template<int MODE>
__global__ __launch_bounds__(256) void gemm_big(
    const float* __restrict__ Aext,
    const float* __restrict__ Bm,
    const float* __restrict__ bias)
{
  const int NR = g_nrows;
  const int m0 = blockIdx.x * 128;
  if (m0 >= NR) return;                      // uniform early exit
  const int n0 = blockIdx.y * 128;

  const int tid = threadIdx.x;
  const int w = tid >> 6, l = tid & 63;
  const int tx = (w & 1) * 8 + (l & 7);      // 0..15 (n dir)
  const int ty = (w >> 1) * 8 + (l >> 3);    // 0..15 (m dir)

  __shared__ float As[2][16][128];           // 16 KB
  __shared__ float Bs[2][16][128];           // 16 KB

  const int ra = tid >> 1, qa = (tid & 1) * 8;   // 128 rows x 16 k, 8 floats/thr

  const float* Abase = (MODE == 0) ? Aext : g_h;
  int mr = m0 + ra; if (mr >= NR) mr = NR - 1;
  const float* aptr = Abase + (size_t)g_rows[mr] * 512 + qa;

  const float* bptr;
  {
    int nrow = n0 + ra;
    if (MODE == 0) bptr = Bm + (size_t)nrow * 512 + qa;
    else bptr = Bm + (nrow < NH5 ? (size_t)nrow * 1024
                                 : (size_t)(nrow - NH5) * 1024 + 512) + qa;
  }

  float4 a0 = *(const float4*)(aptr),     a1 = *(const float4*)(aptr + 4);
  float4 b0 = *(const float4*)(bptr),     b1 = *(const float4*)(bptr + 4);
  float acc[8][8] = {};

  for (int k0 = 0; k0 < 512; k0 += 16) {
    const int buf = (k0 >> 4) & 1;
    As[buf][qa+0][ra]=a0.x; As[buf][qa+1][ra]=a0.y; As[buf][qa+2][ra]=a0.z; As[buf][qa+3][ra]=a0.w;
    As[buf][qa+4][ra]=a1.x; As[buf][qa+5][ra]=a1.y; As[buf][qa+6][ra]=a1.z; As[buf][qa+7][ra]=a1.w;
    Bs[buf][qa+0][ra]=b0.x; Bs[buf][qa+1][ra]=b0.y; Bs[buf][qa+2][ra]=b0.z; Bs[buf][qa+3][ra]=b0.w;
    Bs[buf][qa+4][ra]=b1.x; Bs[buf][qa+5][ra]=b1.y; Bs[buf][qa+6][ra]=b1.z; Bs[buf][qa+7][ra]=b1.w;
    __syncthreads();                         // single barrier per step (dbuf)
    if (k0 + 16 < 512) {
      a0 = *(const float4*)(aptr + k0 + 16); a1 = *(const float4*)(aptr + k0 + 20);
      b0 = *(const float4*)(bptr + k0 + 16); b1 = *(const float4*)(bptr + k0 + 20);
    }
#pragma unroll
    for (int k = 0; k < 16; k++) {
      float af[8], bf[8];
#pragma unroll
      for (int c = 0; c < 2; c++) {
        float4 t = *(const float4*)&As[buf][k][ty*8 + 4*c];
        af[4*c+0]=t.x; af[4*c+1]=t.y; af[4*c+2]=t.z; af[4*c+3]=t.w;
      }
#pragma unroll
      for (int c = 0; c < 2; c++) {
        float4 t = *(const float4*)&Bs[buf][k][tx*8 + 4*c];
        bf[4*c+0]=t.x; bf[4*c+1]=t.y; bf[4*c+2]=t.z; bf[4*c+3]=t.w;
      }
#pragma unroll
      for (int i = 0; i < 8; i++)
#pragma unroll
        for (int j = 0; j < 8; j++)
          acc[i][j] = fmaf(af[i], bf[j], acc[i][j]);
    }
  }

  // vectorized epilogue: per i, two float4 chunks; 8-chunks never straddle
  // the H_/NH5 boundary (both are multiples of 8, chunk base = n0+tx*8)
  const int nb = n0 + tx*8;
  float4 bias_lo, bias_hi;
  if (MODE == 0) { bias_lo = *(const float4*)(bias + nb);
                   bias_hi = *(const float4*)(bias + nb + 4); }
#pragma unroll
  for (int i = 0; i < 8; i++) {
    int mrow = m0 + ty*8 + i;
    if (mrow >= NR) continue;
    int crow = g_rows[mrow];
    float4 v0 = make_float4(acc[i][0], acc[i][1], acc[i][2], acc[i][3]);
    float4 v1 = make_float4(acc[i][4], acc[i][5], acc[i][6], acc[i][7]);
    if (MODE == 0) {
      v0.x += bias_lo.x; v0.y += bias_lo.y; v0.z += bias_lo.z; v0.w += bias_lo.w;
      v1.x += bias_hi.x; v1.y += bias_hi.y; v1.z += bias_hi.z; v1.w += bias_hi.w;
      float* dst = (nb < H_) ? g_h + (size_t)crow*H_ + nb
                             : g_c + (size_t)crow*H_ + (nb - H_);
      *(float4*)(dst) = v0; *(float4*)(dst + 4) = v1;
    } else {
      float* dst = (nb < NH5) ? g_al + (size_t)crow*NH5 + nb
                              : g_ar + (size_t)crow*NH5 + (nb - NH5);
      *(float4*)(dst) = v0; *(float4*)(dst + 4) = v1;
    }
  }
}

// ---------------- iteration-0 logits (R3 verbatim) -------------------------
__global__ __launch_bounds__(256) void iter0_logits(const int* __restrict__ length,
                                                    const float* __restrict__ bc,
                                                    const float* __restrict__ qv) {
  __shared__ float sred[4];
  const int p = blockIdx.x, b = blockIdx.y;
  if (p >= length[b] - 1) return;            // inactive pair: never read
  const float* al = g_al + (size_t)(b*L_ + p)*NH5;
  const float* ar = g_ar + (size_t)(b*L_ + p + 1)*NH5;
  const float* cl = g_c  + (size_t)(b*L_ + p)*H_;
  const float* cr = g_c  + (size_t)(b*L_ + p + 1)*H_;
  float part = 0.f;
#pragma unroll
  for (int jj = 0; jj < H_/256; jj++) {
    int j = threadIdx.x + jj*256;
    float vi  = al[j]       + ar[j]       + bc[j];
    float vfl = al[H_+j]    + ar[H_+j]    + bc[H_+j];
    float vfr = al[2*H_+j]  + ar[2*H_+j]  + bc[2*H_+j];
    float vu  = al[3*H_+j]  + ar[3*H_+j]  + bc[3*H_+j];
    float vo  = al[4*H_+j]  + ar[4*H_+j]  + bc[4*H_+j];
    float c = cl[j]*sigm(vfl+1.f) + cr[j]*sigm(vfr+1.f) + tanhf(vu)*sigm(vi);
    float h = sigm(vo)*tanhf(c);
    part = fmaf(qv[j], h, part);
  }
#pragma unroll
  for (int off = 32; off; off >>= 1) part += __shfl_down(part, off, 64);
  if ((threadIdx.x & 63) == 0) sred[threadIdx.x >> 6] = part;
  __syncthreads();
  if (threadIdx.x == 0)
    g_logit[b*L_ + p] = (sred[0]+sred[1]+sred[2]+sred[3]) * SCALE;
}

// ---------------- per-iteration select + merge (float4 bodies, R4-proven) --
__global__ __launch_bounds__(256) void select_merge(int iter,
    const int* __restrict__ length,
    const float* __restrict__ bc,
    const float* __restrict__ qv,
    float* __restrict__ out)
{
  __shared__ float sred[4];
  __shared__ int s_sel[3];
  const int b = blockIdx.x, tid = threadIdx.x;
  if (b == 0 && tid == 0) g_cnt[(iter & 1) ^ 1] = 0;  // reset next iter's counter

  const int m     = g_count[b];
  const int pslot = g_merged[b];
  const int ppos  = g_mpos[b];
  int* list = g_list + b*L_;

  // ---- refresh the <=2 dirty pairs, half-block each, float4 ----
  if (iter > 0 && pslot >= 0) {
    const int half = tid >> 7, lt = tid & 127;
    int sl = -1, sr = -1;
    if (half == 0) { if (ppos > 0)     { sl = list[ppos-1]; sr = list[ppos];   } }
    else           { if (ppos < m - 1) { sl = list[ppos];   sr = list[ppos+1]; } }
    float part = 0.f;
    if (sl >= 0) {
      const float* al = g_al + (size_t)(b*L_+sl)*NH5;
      const float* ar = g_ar + (size_t)(b*L_+sr)*NH5;
      const float* cl = g_c  + (size_t)(b*L_+sl)*H_;
      const float* cr = g_c  + (size_t)(b*L_+sr)*H_;
      const int j = lt * 4;
      float4 ai  = *(const float4*)(al + j)        , bi  = *(const float4*)(ar + j);
      float4 afl = *(const float4*)(al + H_   + j) , bfl = *(const float4*)(ar + H_   + j);
      float4 afr = *(const float4*)(al + 2*H_ + j) , bfr = *(const float4*)(ar + 2*H_ + j);
      float4 au  = *(const float4*)(al + 3*H_ + j) , bu  = *(const float4*)(ar + 3*H_ + j);
      float4 ao  = *(const float4*)(al + 4*H_ + j) , bo  = *(const float4*)(ar + 4*H_ + j);
      float4 c4l = *(const float4*)(cl + j)        , c4r = *(const float4*)(cr + j);
      float4 q4  = *(const float4*)(qv + j);
      const float* bc0 = bc + j;
      float c, h;
      c = c4l.x*sigm(afl.x+bfl.x+bc0[H_]+1.f)   + c4r.x*sigm(afr.x+bfr.x+bc0[2*H_]+1.f)
        + tanhf(au.x+bu.x+bc0[3*H_])*sigm(ai.x+bi.x+bc0[0]);
      h = sigm(ao.x+bo.x+bc0[4*H_])*tanhf(c);   part = fmaf(q4.x, h, part);
      c = c4l.y*sigm(afl.y+bfl.y+bc0[H_+1]+1.f) + c4r.y*sigm(afr.y+bfr.y+bc0[2*H_+1]+1.f)
        + tanhf(au.y+bu.y+bc0[3*H_+1])*sigm(ai.y+bi.y+bc0[1]);
      h = sigm(ao.y+bo.y+bc0[4*H_+1])*tanhf(c); part = fmaf(q4.y, h, part);
      c = c4l.z*sigm(afl.z+bfl.z+bc0[H_+2]+1.f) + c4r.z*sigm(afr.z+bfr.z+bc0[2*H_+2]+1.f)
        + tanhf(au.z+bu.z+bc0[3*H_+2])*sigm(ai.z+bi.z+bc0[2]);
      h = sigm(ao.z+bo.z+bc0[4*H_+2])*tanhf(c); part = fmaf(q4.z, h, part);
      c = c4l.w*sigm(afl.w+bfl.w+bc0[H_+3]+1.f) + c4r.w*sigm(afr.w+bfr.w+bc0[2*H_+3]+1.f)
        + tanhf(au.w+bu.w+bc0[3*H_+3])*sigm(ai.w+bi.w+bc0[3]);
      h = sigm(ao.w+bo.w+bc0[4*H_+3])*tanhf(c); part = fmaf(q4.w, h, part);
    }
#pragma unroll
    for (int off = 32; off; off >>= 1) part += __shfl_down(part, off, 64);
    if ((tid & 63) == 0) sred[tid >> 6] = part;
    __syncthreads();
    if (tid == 0   && ppos > 0)     g_logit[b*L_ + list[ppos-1]] = (sred[0]+sred[1])*SCALE;
    if (tid == 128 && ppos < m - 1) g_logit[b*L_ + list[ppos]]   = (sred[2]+sred[3])*SCALE;
  }

  const bool active = iter < (length[b] - 1);
  if (active) {
    __syncthreads();   // refreshed g_logit visible block-wide

    // ---- wave-parallel argmax, first-max tie-break (lowest index) ----
    if (tid < 64) {
      float lg = -1e30f; int idx = tid;
      if (tid < m - 1) lg = g_logit[b*L_ + list[tid]];
#pragma unroll
      for (int off = 32; off; off >>= 1) {
        float olg = __shfl_down(lg, off, 64);
        int   oid = __shfl_down(idx, off, 64);
        if (olg > lg || (olg == lg && oid < idx)) { lg = olg; idx = oid; }
      }
      if (tid == 0) { s_sel[0] = idx; s_sel[1] = list[idx]; s_sel[2] = list[idx+1]; }
    }
    __syncthreads();
    const int pos = s_sel[0], sl = s_sel[1], sr = s_sel[2];

    // ---- merge compose: 128 threads x float4 ----
    if (tid < 128) {
      const float* al = g_al + (size_t)(b*L_+sl)*NH5;
      const float* ar = g_ar + (size_t)(b*L_+sr)*NH5;
      float*       cl = g_c  + (size_t)(b*L_+sl)*H_;
      const float* cr = g_c  + (size_t)(b*L_+sr)*H_;
      float*       hl = g_h  + (size_t)(b*L_+sl)*H_;
      const int j = tid * 4;
      float4 ai  = *(const float4*)(al + j)        , bi  = *(const float4*)(ar + j);
      float4 afl = *(const float4*)(al + H_   + j) , bfl = *(const float4*)(ar + H_   + j);
      float4 afr = *(const float4*)(al + 2*H_ + j) , bfr = *(const float4*)(ar + 2*H_ + j);
      float4 au  = *(const float4*)(al + 3*H_ + j) , bu  = *(const float4*)(ar + 3*H_ + j);
      float4 ao  = *(const float4*)(al + 4*H_ + j) , bo  = *(const float4*)(ar + 4*H_ + j);
      float4 c4l = *(const float4*)(cl + j)        , c4r = *(const float4*)(cr + j);
      const float* bc0 = bc + j;
      float4 cn, hn;
      cn.x = c4l.x*sigm(afl.x+bfl.x+bc0[H_]+1.f)   + c4r.x*sigm(afr.x+bfr.x+bc0[2*H_]+1.f)
           + tanhf(au.x+bu.x+bc0[3*H_])*sigm(ai.x+bi.x+bc0[0]);
      hn.x = sigm(ao.x+bo.x+bc0[4*H_])*tanhf(cn.x);
      cn.y = c4l.y*sigm(afl.y+bfl.y+bc0[H_+1]+1.f) + c4r.y*sigm(afr.y+bfr.y+bc0[2*H_+1]+1.f)
           + tanhf(au.y+bu.y+bc0[3*H_+1])*sigm(ai.y+bi.y+bc0[1]);
      hn.y = sigm(ao.y+bo.y+bc0[4*H_+1])*tanhf(cn.y);
      cn.z = c4l.z*sigm(afl.z+bfl.z+bc0[H_+2]+1.f) + c4r.z*sigm(afr.z+bfr.z+bc0[2*H_+2]+1.f)
           + tanhf(au.z+bu.z+bc0[3*H_+2])*sigm(ai.z+bi.z+bc0[2]);
      hn.z = sigm(ao.z+bo.z+bc0[4*H_+2])*tanhf(cn.z);
      cn.w = c4l.w*sigm(afl.w+bfl.w+bc0[H_+3]+1.f) + c4r.w*sigm(afr.w+bfr.w+bc0[2*H_+3]+1.f)
           + tanhf(au.w+bu.w+bc0[3*H_+3])*sigm(ai.w+bi.w+bc0[3]);
      hn.w = sigm(ao.w+bo.w+bc0[4*H_+3])*tanhf(cn.w);
      *(float4*)(cl + j) = cn;
      *(float4*)(hl + j) = hn;
    }
    __syncthreads();
    if (tid == 0) {
      for (int n = pos+1; n < m-1; n++) list[n] = list[n+1];
      g_count[b]  = m - 1;
      g_merged[b] = sl;
      g_mpos[b]   = pos;
      int k = atomicAdd(&g_cnt[iter & 1], 1);
      g_mlist[iter & 1][k] = b;
    }
  } else {
    if (tid == 0) g_merged[b] = -1;
  }

  // ---- folded write_out on the last iteration ----
  if (iter == L_-2) {
    __syncthreads();                         // merge h-write visible (same CU L1)
    for (int j = tid; j < H_; j += 256)
      out[(size_t)b*H_ + j] = g_h[(size_t)(b*L_)*H_ + j];   // root always slot 0
  }
}

// ---------------- per-iteration a_l/a_r GEMM (R3 verbatim) -----------------
__global__ __launch_bounds__(256) void gemm_iter(int par, const float* __restrict__ Wc)
{
  const int nact = g_cnt[par];
  const int m0 = blockIdx.y * 32;
  if (m0 >= nact) return;                    // uniform early exit (handles nact=0)
  const int n0 = blockIdx.x * 64;
  const int tid = threadIdx.x;

  __shared__ float As[32][32];   // [k][m]
  __shared__ float Bs[32][64];   // [k][n]

  const int ra = tid >> 3, qa = (tid & 7) * 4;
  int mr = m0 + ra; if (mr >= nact) mr = nact - 1;
  const int bbA = g_mlist[par][mr];
  const float* aptr = g_h + (size_t)(bbA*L_ + g_merged[bbA]) * 512 + qa;

  const int rb = tid >> 2, qb = (tid & 3) * 8;
  const int nr = n0 + rb;
  const float* bptr = (nr < NH5) ? Wc + (size_t)nr * 1024 + qb
                                 : Wc + (size_t)(nr - NH5) * 1024 + 512 + qb;

  const int tx = tid & 15, ty = tid >> 4;    // 16 n-groups x 16 m-groups

  float4 av  = *(const float4*)(aptr);
  float4 bv0 = *(const float4*)(bptr);
  float4 bv1 = *(const float4*)(bptr + 4);
  float acc[2][4] = {};

  for (int k0 = 0; k0 < 512; k0 += 32) {
    __syncthreads();
    As[qa+0][ra] = av.x;  As[qa+1][ra] = av.y;  As[qa+2][ra] = av.z;  As[qa+3][ra] = av.w;
    Bs[qb+0][rb] = bv0.x; Bs[qb+1][rb] = bv0.y; Bs[qb+2][rb] = bv0.z; Bs[qb+3][rb] = bv0.w;
    Bs[qb+4][rb] = bv1.x; Bs[qb+5][rb] = bv1.y; Bs[qb+6][rb] = bv1.z; Bs[qb+7][rb] = bv1.w;
    __syncthreads();
    if (k0 + 32 < 512) {
      av  = *(const float4*)(aptr + k0 + 32);
      bv0 = *(const float4*)(bptr + k0 + 32);
      bv1 = *(const float4*)(bptr + k0 + 36);
    }
#pragma unroll
    for (int k = 0; k < 32; k++) {
      float2 a2 = *(const float2*)&As[k][ty*2];
      float4 b4 = *(const float4*)&Bs[k][tx*4];
      acc[0][0] = fmaf(a2.x, b4.x, acc[0][0]);
      acc[0][1] = fmaf(a2.x, b4.y, acc[0][1]);
      acc[0][2] = fmaf(a2.x, b4.z, acc[0][2]);
      acc[0][3] = fmaf(a2.x, b4.w, acc[0][3]);
      acc[1][0] = fmaf(a2.y, b4.x, acc[1][0]);
      acc[1][1] = fmaf(a2.y, b4.y, acc[1][1]);
      acc[1][2] = fmaf(a2.y, b4.z, acc[1][2]);
      acc[1][3] = fmaf(a2.y, b4.w, acc[1][3]);
    }
  }

#pragma unroll
  for (int i = 0; i < 2; i++) {
    int mrow = m0 + ty*2 + i;
    if (mrow >= nact) continue;
    int bb = g_mlist[par][mrow];
    size_t base = (size_t)(bb*L_ + g_merged[bb]) * NH5;
    int n = n0 + tx*4;                       // 4-chunks never straddle NH5
    float4 v = make_float4(acc[i][0], acc[i][1], acc[i][2], acc[i][3]);
    if (n < NH5) *(float4*)(g_al + base + n)         = v;
    else         *(float4*)(g_ar + base + (n - NH5)) = v;
  }
}

// ---------------------------------------------------------------------------
extern "C" void kernel_launch(void* const* d_in, const int* in_sizes, int n_in,
                              void* d_out, int out_size, void* d_ws, size_t ws_size,
                              hipStream_t stream)
{
  (void)in_sizes; (void)n_in; (void)out_size; (void)d_ws; (void)ws_size;
  const float* x      = (const float*)d_in[0];
  const int*   length = (const int*)  d_in[1];
  const float* W_word = (const float*)d_in[2];
  const float* b_word = (const float*)d_in[3];
  const float* W_comp = (const float*)d_in[4];
  const float* b_comp = (const float*)d_in[5];
  const float* q      = (const float*)d_in[6];
  float* out = (float*)d_out;

  init_all<<<1, 256, 0, stream>>>(length);

  gemm_big<0><<<dim3(64, 1024/128), 256, 0, stream>>>(x, W_word, b_word);
  gemm_big<1><<<dim3(64, N2/128),   256, 0, stream>>>(nullptr, W_comp, nullptr);

  iter0_logits<<<dim3(L_-1, B_), 256, 0, stream>>>(length, b_comp, q);

  for (int i = 0; i < L_-1; i++) {
    select_merge<<<B_, 256, 0, stream>>>(i, length, b_comp, q, out);
    if (i < L_-2)
      gemm_iter<<<dim3(N2/64, 8), 256, 0, stream>>>(i & 1, W_comp);
  }
}

// Round 7
// 1685.577 us; speedup vs baseline: 4.4314x; 1.0396x over previous
//
#include <hip/hip_runtime.h>
#include <cmath>

// (B, L, D, H) = (256, 32, 512, 512)
#define B_   256
#define L_   32
#define H_   512
#define NH5  2560   // 5*H
#define N2   5120   // 2*NH5 : [al | ar] output width
#define SCALE 0.044194173824159216f  // 1/sqrt(H)

// ---------------- persistent device state (re-initialized every launch) ----
__device__ float g_h [B_*L_*H_];          // [b][slot][j] node hidden
__device__ float g_c [B_*L_*H_];          // [b][slot][j] node cell
__device__ float g_al[(size_t)B_*L_*NH5]; // [b][slot][k] Wl @ h_slot
__device__ float g_ar[(size_t)B_*L_*NH5]; // [b][slot][k] Wr @ h_slot
__device__ float g_logit[B_*L_];          // pair logit keyed by LEFT slot
__device__ int   g_list[B_*L_];           // active slot list (sequence order)
__device__ int   g_count[B_];             // active node count
__device__ int   g_merged[B_];            // slot merged last iter (-1 done, -2 init)
__device__ int   g_mpos[B_];              // list position of last merge
__device__ int   g_off[B_];               // exclusive prefix of lengths
__device__ int   g_rows[B_*L_];           // ordered compact list of active rows
__device__ int   g_nrows;
__device__ int   g_mlist[2][B_];          // batches merged this iter (parity)
__device__ int   g_cnt[2];

__device__ __forceinline__ float sigm(float x) { return 1.0f / (1.0f + expf(-x)); }

// ---------------- init: prefix-scan lengths + fill lists (one dispatch) ----
__global__ __launch_bounds__(256) void init_all(const int* __restrict__ length) {
  __shared__ int sw[4];
  const int t = threadIdx.x;
  const int len = length[t];
  int v = len;
#pragma unroll
  for (int off = 1; off < 64; off <<= 1) {
    int o = __shfl_up(v, off, 64);
    if ((t & 63) >= off) v += o;
  }
  if ((t & 63) == 63) sw[t >> 6] = v;
  __syncthreads();
  int base = 0;
  for (int w = 0; w < (t >> 6); w++) base += sw[w];
  const int incl = base + v;
  const int off0 = incl - len;
  g_off[t] = off0;
  if (t == 255) g_nrows = incl;
  g_count[t] = len; g_merged[t] = -2; g_mpos[t] = 0;
  if (t == 0) { g_cnt[0] = 0; g_cnt[1] = 0; }
#pragma unroll
  for (int s = 0; s < L_; s++) g_list[t*L_ + s] = s;
  for (int s = 0; s < len; s++) g_rows[off0 + s] = t*L_ + s;  // sorted by (b,slot)
}

// ---------------- big row-compacted GEMMs (R3-proven: 128x128, BK=8) -------
// MODE 0: word GEMM  A=x rows   -> g_h|g_c (+b_word)   N=1024
// MODE 1: leaf GEMM  A=g_h rows -> g_al|g_ar           N=5120
// grid: x = n-tiles, y = m-tiles (R3 order). LDS 8 KB, occupancy-friendly.
template<int MODE>
__global__ __launch_bounds__(256) void gemm_big(
    const float* __restrict__ Aext,
    const float* __restrict__ Bm,
    const float* __restrict__ bias)
{
  const int NR = g_nrows;
  const int m0 = blockIdx.y * 128;
  if (m0 >= NR) return;                      // uniform early exit
  const int n0 = blockIdx.x * 128;

  const int tid = threadIdx.x;
  const int w = tid >> 6, l = tid & 63;
  const int tx = (w & 1) * 8 + (l & 7);      // 0..15 (n dir)
  const int ty = (w >> 1) * 8 + (l >> 3);    // 0..15 (m dir)

  __shared__ float As[8][128];               // 4 KB
  __shared__ float Bs[8][128];               // 4 KB

  const int ra = tid >> 1, qa = (tid & 1) * 4;   // 128 rows x 2 float4 chunks

  const float* Abase = (MODE == 0) ? Aext : g_h;
  int mr = m0 + ra; if (mr >= NR) mr = NR - 1;
  const float* aptr = Abase + (size_t)g_rows[mr] * 512 + qa;

  const float* bptr;
  {
    int nrow = n0 + ra;
    if (MODE == 0) bptr = Bm + (size_t)nrow * 512 + qa;
    else bptr = Bm + (nrow < NH5 ? (size_t)nrow * 1024
                                 : (size_t)(nrow - NH5) * 1024 + 512) + qa;
  }

  // register-prefetch pipeline: loads for k0+8 issue behind compute of k0
  float4 av = *(const float4*)(aptr);
  float4 bv = *(const float4*)(bptr);
  float acc[8][8] = {};

  for (int k0 = 0; k0 < 512; k0 += 8) {
    __syncthreads();
    As[qa+0][ra] = av.x; As[qa+1][ra] = av.y; As[qa+2][ra] = av.z; As[qa+3][ra] = av.w;
    Bs[qa+0][ra] = bv.x; Bs[qa+1][ra] = bv.y; Bs[qa+2][ra] = bv.z; Bs[qa+3][ra] = bv.w;
    __syncthreads();
    if (k0 + 8 < 512) {
      av = *(const float4*)(aptr + k0 + 8);
      bv = *(const float4*)(bptr + k0 + 8);
    }
#pragma unroll
    for (int k = 0; k < 8; k++) {
      float af[8], bf[8];
#pragma unroll
      for (int c = 0; c < 2; c++) {
        float4 t = *(const float4*)&As[k][ty*8 + 4*c];
        af[4*c+0]=t.x; af[4*c+1]=t.y; af[4*c+2]=t.z; af[4*c+3]=t.w;
      }
#pragma unroll
      for (int c = 0; c < 2; c++) {
        float4 t = *(const float4*)&Bs[k][tx*8 + 4*c];
        bf[4*c+0]=t.x; bf[4*c+1]=t.y; bf[4*c+2]=t.z; bf[4*c+3]=t.w;
      }
#pragma unroll
      for (int i = 0; i < 8; i++)
#pragma unroll
        for (int j = 0; j < 8; j++)
          acc[i][j] = fmaf(af[i], bf[j], acc[i][j]);
    }
  }

  // float4 epilogue: chunk base nb is 8-aligned; H_/NH5 are multiples of 8,
  // so an 8-wide chunk never straddles the h|c (or al|ar) boundary.
  const int nb = n0 + tx*8;
  float4 bias_lo, bias_hi;
  if (MODE == 0) { bias_lo = *(const float4*)(bias + nb);
                   bias_hi = *(const float4*)(bias + nb + 4); }
#pragma unroll
  for (int i = 0; i < 8; i++) {
    int mrow = m0 + ty*8 + i;
    if (mrow >= NR) continue;
    int crow = g_rows[mrow];
    float4 v0 = make_float4(acc[i][0], acc[i][1], acc[i][2], acc[i][3]);
    float4 v1 = make_float4(acc[i][4], acc[i][5], acc[i][6], acc[i][7]);
    if (MODE == 0) {
      v0.x += bias_lo.x; v0.y += bias_lo.y; v0.z += bias_lo.z; v0.w += bias_lo.w;
      v1.x += bias_hi.x; v1.y += bias_hi.y; v1.z += bias_hi.z; v1.w += bias_hi.w;
      float* dst = (nb < H_) ? g_h + (size_t)crow*H_ + nb
                             : g_c + (size_t)crow*H_ + (nb - H_);
      *(float4*)(dst) = v0; *(float4*)(dst + 4) = v1;
    } else {
      float* dst = (nb < NH5) ? g_al + (size_t)crow*NH5 + nb
                              : g_ar + (size_t)crow*NH5 + (nb - NH5);
      *(float4*)(dst) = v0; *(float4*)(dst + 4) = v1;
    }
  }
}

// ---------------- iteration-0 logits ---------------------------------------
__global__ __launch_bounds__(256) void iter0_logits(const int* __restrict__ length,
                                                    const float* __restrict__ bc,
                                                    const float* __restrict__ qv) {
  __shared__ float sred[4];
  const int p = blockIdx.x, b = blockIdx.y;
  if (p >= length[b] - 1) return;            // inactive pair: never read
  const float* al = g_al + (size_t)(b*L_ + p)*NH5;
  const float* ar = g_ar + (size_t)(b*L_ + p + 1)*NH5;
  const float* cl = g_c  + (size_t)(b*L_ + p)*H_;
  const float* cr = g_c  + (size_t)(b*L_ + p + 1)*H_;
  float part = 0.f;
#pragma unroll
  for (int jj = 0; jj < H_/256; jj++) {
    int j = threadIdx.x + jj*256;
    float vi  = al[j]       + ar[j]       + bc[j];
    float vfl = al[H_+j]    + ar[H_+j]    + bc[H_+j];
    float vfr = al[2*H_+j]  + ar[2*H_+j]  + bc[2*H_+j];
    float vu  = al[3*H_+j]  + ar[3*H_+j]  + bc[3*H_+j];
    float vo  = al[4*H_+j]  + ar[4*H_+j]  + bc[4*H_+j];
    float c = cl[j]*sigm(vfl+1.f) + cr[j]*sigm(vfr+1.f) + tanhf(vu)*sigm(vi);
    float h = sigm(vo)*tanhf(c);
    part = fmaf(qv[j], h, part);
  }
#pragma unroll
  for (int off = 32; off; off >>= 1) part += __shfl_down(part, off, 64);
  if ((threadIdx.x & 63) == 0) sred[threadIdx.x >> 6] = part;
  __syncthreads();
  if (threadIdx.x == 0)
    g_logit[b*L_ + p] = (sred[0]+sred[1]+sred[2]+sred[3]) * SCALE;
}

// ---------------- per-iteration select + merge (float4 bodies) -------------
__global__ __launch_bounds__(256) void select_merge(int iter,
    const int* __restrict__ length,
    const float* __restrict__ bc,
    const float* __restrict__ qv,
    float* __restrict__ out)
{
  __shared__ float sred[4];
  __shared__ int s_sel[3];
  const int b = blockIdx.x, tid = threadIdx.x;
  if (b == 0 && tid == 0) g_cnt[(iter & 1) ^ 1] = 0;  // reset next iter's counter

  const int m     = g_count[b];
  const int pslot = g_merged[b];
  const int ppos  = g_mpos[b];
  int* list = g_list + b*L_;

  // ---- refresh the <=2 dirty pairs, half-block each, float4 ----
  if (iter > 0 && pslot >= 0) {
    const int half = tid >> 7, lt = tid & 127;
    int sl = -1, sr = -1;
    if (half == 0) { if (ppos > 0)     { sl = list[ppos-1]; sr = list[ppos];   } }
    else           { if (ppos < m - 1) { sl = list[ppos];   sr = list[ppos+1]; } }
    float part = 0.f;
    if (sl >= 0) {
      const float* al = g_al + (size_t)(b*L_+sl)*NH5;
      const float* ar = g_ar + (size_t)(b*L_+sr)*NH5;
      const float* cl = g_c  + (size_t)(b*L_+sl)*H_;
      const float* cr = g_c  + (size_t)(b*L_+sr)*H_;
      const int j = lt * 4;
      float4 ai  = *(const float4*)(al + j)        , bi  = *(const float4*)(ar + j);
      float4 afl = *(const float4*)(al + H_   + j) , bfl = *(const float4*)(ar + H_   + j);
      float4 afr = *(const float4*)(al + 2*H_ + j) , bfr = *(const float4*)(ar + 2*H_ + j);
      float4 au  = *(const float4*)(al + 3*H_ + j) , bu  = *(const float4*)(ar + 3*H_ + j);
      float4 ao  = *(const float4*)(al + 4*H_ + j) , bo  = *(const float4*)(ar + 4*H_ + j);
      float4 c4l = *(const float4*)(cl + j)        , c4r = *(const float4*)(cr + j);
      float4 q4  = *(const float4*)(qv + j);
      const float* bc0 = bc + j;
      float c, h;
      c = c4l.x*sigm(afl.x+bfl.x+bc0[H_]+1.f)   + c4r.x*sigm(afr.x+bfr.x+bc0[2*H_]+1.f)
        + tanhf(au.x+bu.x+bc0[3*H_])*sigm(ai.x+bi.x+bc0[0]);
      h = sigm(ao.x+bo.x+bc0[4*H_])*tanhf(c);   part = fmaf(q4.x, h, part);
      c = c4l.y*sigm(afl.y+bfl.y+bc0[H_+1]+1.f) + c4r.y*sigm(afr.y+bfr.y+bc0[2*H_+1]+1.f)
        + tanhf(au.y+bu.y+bc0[3*H_+1])*sigm(ai.y+bi.y+bc0[1]);
      h = sigm(ao.y+bo.y+bc0[4*H_+1])*tanhf(c); part = fmaf(q4.y, h, part);
      c = c4l.z*sigm(afl.z+bfl.z+bc0[H_+2]+1.f) + c4r.z*sigm(afr.z+bfr.z+bc0[2*H_+2]+1.f)
        + tanhf(au.z+bu.z+bc0[3*H_+2])*sigm(ai.z+bi.z+bc0[2]);
      h = sigm(ao.z+bo.z+bc0[4*H_+2])*tanhf(c); part = fmaf(q4.z, h, part);
      c = c4l.w*sigm(afl.w+bfl.w+bc0[H_+3]+1.f) + c4r.w*sigm(afr.w+bfr.w+bc0[2*H_+3]+1.f)
        + tanhf(au.w+bu.w+bc0[3*H_+3])*sigm(ai.w+bi.w+bc0[3]);
      h = sigm(ao.w+bo.w+bc0[4*H_+3])*tanhf(c); part = fmaf(q4.w, h, part);
    }
#pragma unroll
    for (int off = 32; off; off >>= 1) part += __shfl_down(part, off, 64);
    if ((tid & 63) == 0) sred[tid >> 6] = part;
    __syncthreads();
    if (tid == 0   && ppos > 0)     g_logit[b*L_ + list[ppos-1]] = (sred[0]+sred[1])*SCALE;
    if (tid == 128 && ppos < m - 1) g_logit[b*L_ + list[ppos]]   = (sred[2]+sred[3])*SCALE;
  }

  const bool active = iter < (length[b] - 1);
  if (active) {
    __syncthreads();   // refreshed g_logit visible block-wide

    // ---- wave-parallel argmax, first-max tie-break (lowest index) ----
    if (tid < 64) {
      float lg = -1e30f; int idx = tid;
      if (tid < m - 1) lg = g_logit[b*L_ + list[tid]];
#pragma unroll
      for (int off = 32; off; off >>= 1) {
        float olg = __shfl_down(lg, off, 64);
        int   oid = __shfl_down(idx, off, 64);
        if (olg > lg || (olg == lg && oid < idx)) { lg = olg; idx = oid; }
      }
      if (tid == 0) { s_sel[0] = idx; s_sel[1] = list[idx]; s_sel[2] = list[idx+1]; }
    }
    __syncthreads();
    const int pos = s_sel[0], sl = s_sel[1], sr = s_sel[2];

    // ---- merge compose: 128 threads x float4 ----
    if (tid < 128) {
      const float* al = g_al + (size_t)(b*L_+sl)*NH5;
      const float* ar = g_ar + (size_t)(b*L_+sr)*NH5;
      float*       cl = g_c  + (size_t)(b*L_+sl)*H_;
      const float* cr = g_c  + (size_t)(b*L_+sr)*H_;
      float*       hl = g_h  + (size_t)(b*L_+sl)*H_;
      const int j = tid * 4;
      float4 ai  = *(const float4*)(al + j)        , bi  = *(const float4*)(ar + j);
      float4 afl = *(const float4*)(al + H_   + j) , bfl = *(const float4*)(ar + H_   + j);
      float4 afr = *(const float4*)(al + 2*H_ + j) , bfr = *(const float4*)(ar + 2*H_ + j);
      float4 au  = *(const float4*)(al + 3*H_ + j) , bu  = *(const float4*)(ar + 3*H_ + j);
      float4 ao  = *(const float4*)(al + 4*H_ + j) , bo  = *(const float4*)(ar + 4*H_ + j);
      float4 c4l = *(const float4*)(cl + j)        , c4r = *(const float4*)(cr + j);
      const float* bc0 = bc + j;
      float4 cn, hn;
      cn.x = c4l.x*sigm(afl.x+bfl.x+bc0[H_]+1.f)   + c4r.x*sigm(afr.x+bfr.x+bc0[2*H_]+1.f)
           + tanhf(au.x+bu.x+bc0[3*H_])*sigm(ai.x+bi.x+bc0[0]);
      hn.x = sigm(ao.x+bo.x+bc0[4*H_])*tanhf(cn.x);
      cn.y = c4l.y*sigm(afl.y+bfl.y+bc0[H_+1]+1.f) + c4r.y*sigm(afr.y+bfr.y+bc0[2*H_+1]+1.f)
           + tanhf(au.y+bu.y+bc0[3*H_+1])*sigm(ai.y+bi.y+bc0[1]);
      hn.y = sigm(ao.y+bo.y+bc0[4*H_+1])*tanhf(cn.y);
      cn.z = c4l.z*sigm(afl.z+bfl.z+bc0[H_+2]+1.f) + c4r.z*sigm(afr.z+bfr.z+bc0[2*H_+2]+1.f)
           + tanhf(au.z+bu.z+bc0[3*H_+2])*sigm(ai.z+bi.z+bc0[2]);
      hn.z = sigm(ao.z+bo.z+bc0[4*H_+2])*tanhf(cn.z);
      cn.w = c4l.w*sigm(afl.w+bfl.w+bc0[H_+3]+1.f) + c4r.w*sigm(afr.w+bfr.w+bc0[2*H_+3]+1.f)
           + tanhf(au.w+bu.w+bc0[3*H_+3])*sigm(ai.w+bi.w+bc0[3]);
      hn.w = sigm(ao.w+bo.w+bc0[4*H_+3])*tanhf(cn.w);
      *(float4*)(cl + j) = cn;
      *(float4*)(hl + j) = hn;
    }
    __syncthreads();
    if (tid == 0) {
      for (int n = pos+1; n < m-1; n++) list[n] = list[n+1];
      g_count[b]  = m - 1;
      g_merged[b] = sl;
      g_mpos[b]   = pos;
      int k = atomicAdd(&g_cnt[iter & 1], 1);
      g_mlist[iter & 1][k] = b;
    }
  } else {
    if (tid == 0) g_merged[b] = -1;
  }

  // ---- folded write_out on the last iteration ----
  if (iter == L_-2) {
    __syncthreads();                         // merge h-write visible block-wide
    for (int j = tid; j < H_; j += 256)
      out[(size_t)b*H_ + j] = g_h[(size_t)(b*L_)*H_ + j];   // root always slot 0
  }
}

// ---------------- per-iteration a_l/a_r GEMM (R3-proven) -------------------
__global__ __launch_bounds__(256) void gemm_iter(int par, const float* __restrict__ Wc)
{
  const int nact = g_cnt[par];
  const int m0 = blockIdx.y * 32;
  if (m0 >= nact) return;                    // uniform early exit (handles nact=0)
  const int n0 = blockIdx.x * 64;
  const int tid = threadIdx.x;

  __shared__ float As[32][32];   // [k][m]
  __shared__ float Bs[32][64];   // [k][n]

  const int ra = tid >> 3, qa = (tid & 7) * 4;
  int mr = m0 + ra; if (mr >= nact) mr = nact - 1;
  const int bbA = g_mlist[par][mr];
  const float* aptr = g_h + (size_t)(bbA*L_ + g_merged[bbA]) * 512 + qa;

  const int rb = tid >> 2, qb = (tid & 3) * 8;
  const int nr = n0 + rb;
  const float* bptr = (nr < NH5) ? Wc + (size_t)nr * 1024 + qb
                                 : Wc + (size_t)(nr - NH5) * 1024 + 512 + qb;

  const int tx = tid & 15, ty = tid >> 4;    // 16 n-groups x 16 m-groups

  float4 av  = *(const float4*)(aptr);
  float4 bv0 = *(const float4*)(bptr);
  float4 bv1 = *(const float4*)(bptr + 4);
  float acc[2][4] = {};

  for (int k0 = 0; k0 < 512; k0 += 32) {
    __syncthreads();
    As[qa+0][ra] = av.x;  As[qa+1][ra] = av.y;  As[qa+2][ra] = av.z;  As[qa+3][ra] = av.w;
    Bs[qb+0][rb] = bv0.x; Bs[qb+1][rb] = bv0.y; Bs[qb+2][rb] = bv0.z; Bs[qb+3][rb] = bv0.w;
    Bs[qb+4][rb] = bv1.x; Bs[qb+5][rb] = bv1.y; Bs[qb+6][rb] = bv1.z; Bs[qb+7][rb] = bv1.w;
    __syncthreads();
    if (k0 + 32 < 512) {
      av  = *(const float4*)(aptr + k0 + 32);
      bv0 = *(const float4*)(bptr + k0 + 32);
      bv1 = *(const float4*)(bptr + k0 + 36);
    }
#pragma unroll
    for (int k = 0; k < 32; k++) {
      float2 a2 = *(const float2*)&As[k][ty*2];
      float4 b4 = *(const float4*)&Bs[k][tx*4];
      acc[0][0] = fmaf(a2.x, b4.x, acc[0][0]);
      acc[0][1] = fmaf(a2.x, b4.y, acc[0][1]);
      acc[0][2] = fmaf(a2.x, b4.z, acc[0][2]);
      acc[0][3] = fmaf(a2.x, b4.w, acc[0][3]);
      acc[1][0] = fmaf(a2.y, b4.x, acc[1][0]);
      acc[1][1] = fmaf(a2.y, b4.y, acc[1][1]);
      acc[1][2] = fmaf(a2.y, b4.z, acc[1][2]);
      acc[1][3] = fmaf(a2.y, b4.w, acc[1][3]);
    }
  }

#pragma unroll
  for (int i = 0; i < 2; i++) {
    int mrow = m0 + ty*2 + i;
    if (mrow >= nact) continue;
    int bb = g_mlist[par][mrow];
    size_t base = (size_t)(bb*L_ + g_merged[bb]) * NH5;
    int n = n0 + tx*4;                       // 4-chunks never straddle NH5
    float4 v = make_float4(acc[i][0], acc[i][1], acc[i][2], acc[i][3]);
    if (n < NH5) *(float4*)(g_al + base + n)         = v;
    else         *(float4*)(g_ar + base + (n - NH5)) = v;
  }
}

// ---------------------------------------------------------------------------
extern "C" void kernel_launch(void* const* d_in, const int* in_sizes, int n_in,
                              void* d_out, int out_size, void* d_ws, size_t ws_size,
                              hipStream_t stream)
{
  (void)in_sizes; (void)n_in; (void)out_size; (void)d_ws; (void)ws_size;
  const float* x      = (const float*)d_in[0];
  const int*   length = (const int*)  d_in[1];
  const float* W_word = (const float*)d_in[2];
  const float* b_word = (const float*)d_in[3];
  const float* W_comp = (const float*)d_in[4];
  const float* b_comp = (const float*)d_in[5];
  const float* q      = (const float*)d_in[6];
  float* out = (float*)d_out;

  init_all<<<1, 256, 0, stream>>>(length);

  gemm_big<0><<<dim3(1024/128, 64), 256, 0, stream>>>(x, W_word, b_word);
  gemm_big<1><<<dim3(N2/128,   64), 256, 0, stream>>>(nullptr, W_comp, nullptr);

  iter0_logits<<<dim3(L_-1, B_), 256, 0, stream>>>(length, b_comp, q);

  for (int i = 0; i < L_-1; i++) {
    select_merge<<<B_, 256, 0, stream>>>(i, length, b_comp, q, out);
    if (i < L_-2)
      gemm_iter<<<dim3(N2/64, 8), 256, 0, stream>>>(i & 1, W_comp);
  }
}